// Round 7
// baseline (65.114 us; speedup 1.0000x reference)
//
#include <hip/hip_runtime.h>
#include <hip/hip_bf16.h>

#define B 4
#define S 2048
#define D 512
#define P 16
#define NC 64   // chunks over sequence
#define CL 32   // chunk length = S/NC

// ---------------------------------------------------------------------------
// Kernel 1: prods[b,s,p] = dot(proxy[p,:], x[b,s,:]); w = softmax_p(prods/4).
// One wave per (b,s) row. Lane l owns proxy row p = l&15 and d-slice
// q = l>>4 (128 floats): scalar partial per lane, then a 2-shuffle cross-slice
// reduce. Result lands with lane l holding p = l&15 — no butterfly tree.
// Shuffles per wave: 10 (was 104).
// ---------------------------------------------------------------------------
__global__ __launch_bounds__(256) void k_prods(const float* __restrict__ x,
                                               const float* __restrict__ proxy,
                                               float* __restrict__ prods,
                                               float* __restrict__ wgt) {
    int wid  = (blockIdx.x * blockDim.x + threadIdx.x) >> 6;  // bs index
    int lane = threadIdx.x & 63;
    if (wid >= B * S) return;

    const int p = lane & 15;
    const int q = lane >> 4;          // d-slice 0..3, 128 floats each

    const float4* xr = (const float4*)(x     + (size_t)wid * D + q * 128);
    const float4* pr = (const float4*)(proxy + (size_t)p   * D + q * 128);

    float a0 = 0.f, a1 = 0.f, a2 = 0.f, a3 = 0.f;
#pragma unroll 8
    for (int i = 0; i < 32; i += 4) {
        float4 xa0 = xr[i+0], pa0 = pr[i+0];
        float4 xa1 = xr[i+1], pa1 = pr[i+1];
        float4 xa2 = xr[i+2], pa2 = pr[i+2];
        float4 xa3 = xr[i+3], pa3 = pr[i+3];
        a0 = fmaf(xa0.x, pa0.x, a0); a0 = fmaf(xa0.y, pa0.y, a0);
        a0 = fmaf(xa0.z, pa0.z, a0); a0 = fmaf(xa0.w, pa0.w, a0);
        a1 = fmaf(xa1.x, pa1.x, a1); a1 = fmaf(xa1.y, pa1.y, a1);
        a1 = fmaf(xa1.z, pa1.z, a1); a1 = fmaf(xa1.w, pa1.w, a1);
        a2 = fmaf(xa2.x, pa2.x, a2); a2 = fmaf(xa2.y, pa2.y, a2);
        a2 = fmaf(xa2.z, pa2.z, a2); a2 = fmaf(xa2.w, pa2.w, a2);
        a3 = fmaf(xa3.x, pa3.x, a3); a3 = fmaf(xa3.y, pa3.y, a3);
        a3 = fmaf(xa3.z, pa3.z, a3); a3 = fmaf(xa3.w, pa3.w, a3);
    }
    float acc = (a0 + a1) + (a2 + a3);

    // cross-slice reduce: lanes differing in bits 4,5 hold same p
    acc += __shfl_xor(acc, 16);
    acc += __shfl_xor(acc, 32);
    // lane l now holds the full dot for p = l&15 (replicated over q)

    // softmax over the 16-lane p-group
    float m = acc;
#pragma unroll
    for (int off = 1; off < 16; off <<= 1) m = fmaxf(m, __shfl_xor(m, off));
    float e = __expf((acc - m) * 0.25f);
    float den = e;
#pragma unroll
    for (int off = 1; off < 16; off <<= 1) den += __shfl_xor(den, off);

    if (lane < P) {
        prods[(size_t)wid * P + lane] = acc;
        wgt  [(size_t)wid * P + lane] = e / den;
    }
}

// ---------------------------------------------------------------------------
// Kernel 2: chunk totals T[b,c,p,d] (R4 verbatim). Block = (b,c,half).
// ---------------------------------------------------------------------------
__global__ __launch_bounds__(256) void k_totals(const float* __restrict__ x,
                                                const float* __restrict__ prods,
                                                float* __restrict__ T) {
    int h = blockIdx.x & 1;
    int c = (blockIdx.x >> 1) & (NC - 1);
    int b = blockIdx.x >> 7;
    int d = h * 256 + threadIdx.x;

    float acc[P];
#pragma unroll
    for (int p = 0; p < P; ++p) acc[p] = 0.f;

    int bs0 = b * S + c * CL;
#pragma unroll 4
    for (int i = 0; i < CL; ++i) {
        int bs = bs0 + i;
        float xv = x[(size_t)bs * D + d];
        const float4* pp = (const float4*)(prods + (size_t)bs * P);
        float pr[P];
        ((float4*)pr)[0] = pp[0];
        ((float4*)pr)[1] = pp[1];
        ((float4*)pr)[2] = pp[2];
        ((float4*)pr)[3] = pp[3];
#pragma unroll
        for (int p = 0; p < P; ++p) acc[p] = fmaf(pr[p], xv, acc[p]);
    }
    size_t tb = ((size_t)(b * NC + c)) * (P * D) + d;
#pragma unroll
    for (int p = 0; p < P; ++p) T[tb + p * D] = acc[p];
}

// ---------------------------------------------------------------------------
// Kernel 3: in-place exclusive prefix over chunks (R4 verbatim).
// ---------------------------------------------------------------------------
__global__ __launch_bounds__(256) void k_scan(float* __restrict__ T) {
    int t = blockIdx.x * blockDim.x + threadIdx.x;   // ((b*P+p)*D + d)
    int d = t & (D - 1);
    int p = (t >> 9) & (P - 1);
    int b = t >> 13;
    size_t base = ((size_t)b * NC * P + p) * D + d;
    float run = 0.f;
#pragma unroll 8
    for (int c = 0; c < NC; ++c) {
        size_t idx = base + (size_t)c * (P * D);
        float v = T[idx];
        T[idx] = run;
        run += v;
    }
}

// ---------------------------------------------------------------------------
// Kernel 4: apply (R4 verbatim). Block = (b,c,half), 256 threads.
// ---------------------------------------------------------------------------
__global__ __launch_bounds__(256) void k_apply(const float* __restrict__ x,
                                               const float* __restrict__ prods,
                                               const float* __restrict__ wgt,
                                               const float* __restrict__ T,
                                               float* __restrict__ out) {
    int h = blockIdx.x & 1;
    int c = (blockIdx.x >> 1) & (NC - 1);
    int b = blockIdx.x >> 7;
    int d = h * 256 + threadIdx.x;

    float st[P];
    size_t tb = ((size_t)(b * NC + c)) * (P * D) + d;
#pragma unroll
    for (int p = 0; p < P; ++p) st[p] = T[tb + p * D];

    int bs0 = b * S + c * CL;
#pragma unroll 2
    for (int i = 0; i < CL; ++i) {
        int bs = bs0 + i;
        float xv = x[(size_t)bs * D + d];
        const float4* pp = (const float4*)(prods + (size_t)bs * P);
        const float4* wp = (const float4*)(wgt   + (size_t)bs * P);
        float pr[P], ww[P];
        ((float4*)pr)[0] = pp[0];
        ((float4*)pr)[1] = pp[1];
        ((float4*)pr)[2] = pp[2];
        ((float4*)pr)[3] = pp[3];
        ((float4*)ww)[0] = wp[0];
        ((float4*)ww)[1] = wp[1];
        ((float4*)ww)[2] = wp[2];
        ((float4*)ww)[3] = wp[3];
        float o = 0.f;
#pragma unroll
        for (int p = 0; p < P; ++p) {
            st[p] = fmaf(pr[p], xv, st[p]);
            o = fmaf(ww[p], st[p], o);
        }
        out[(size_t)bs * D + d] = o;
    }
}

extern "C" void kernel_launch(void* const* d_in, const int* in_sizes, int n_in,
                              void* d_out, int out_size, void* d_ws, size_t ws_size,
                              hipStream_t stream) {
    const float* x     = (const float*)d_in[0];
    const float* proxy = (const float*)d_in[1];
    float* out   = (float*)d_out;

    float* prods = (float*)d_ws;                 // B*S*P floats = 512 KiB
    float* wgt   = prods + (size_t)B * S * P;    // 512 KiB
    float* T     = wgt   + (size_t)B * S * P;    // B*NC*P*D floats = 8 MiB

    k_prods <<<(B * S) / 4,       256, 0, stream>>>(x, proxy, prods, wgt);
    k_totals<<<B * NC * 2,        256, 0, stream>>>(x, prods, T);
    k_scan  <<<(B * P * D) / 256, 256, 0, stream>>>(T);
    k_apply <<<B * NC * 2,        256, 0, stream>>>(x, prods, wgt, T, out);
}

// Round 8
// 64.072 us; speedup vs baseline: 1.0163x; 1.0163x over previous
//
#include <hip/hip_runtime.h>
#include <hip/hip_bf16.h>

#define B 4
#define S 2048
#define D 512
#define P 16
#define NC 64   // chunks over sequence
#define CL 32   // chunk length = S/NC

// ---------------------------------------------------------------------------
// Kernel 1: prods[b,s,p] = dot(proxy[p,:], x[b,s,:]); w = softmax_p(prods/4).
// Block = 256 threads = 16 rows x 16 proxies; thread t owns (r=t>>4, p=t&15)
// and computes the full 512-FMA dot alone (no reduction tree).
//  - x loads: quarter-wave broadcast (4 unique 16B lines / instr, HW-merged)
//  - proxy loads: 16 lines / instr, L1-resident (32 KB total)
//  - only 8 shuffles per wave (16-lane softmax), vs 96 in the butterfly
// ---------------------------------------------------------------------------
__global__ __launch_bounds__(256) void k_prods(const float* __restrict__ x,
                                               const float* __restrict__ proxy,
                                               float* __restrict__ prods,
                                               float* __restrict__ wgt) {
    const int t  = threadIdx.x;
    const int p  = t & 15;
    const int r  = t >> 4;                 // 0..15
    const int bs = blockIdx.x * 16 + r;    // grid = B*S/16

    const float4* xr = (const float4*)(x     + (size_t)bs * D);
    const float4* pr = (const float4*)(proxy + (size_t)p  * D);

    float ax = 0.f, ay = 0.f, az = 0.f, aw = 0.f;
#pragma unroll 8
    for (int i = 0; i < D / 4; ++i) {
        float4 xv = xr[i];
        float4 pv = pr[i];
        ax = fmaf(xv.x, pv.x, ax);
        ay = fmaf(xv.y, pv.y, ay);
        az = fmaf(xv.z, pv.z, az);
        aw = fmaf(xv.w, pv.w, aw);
    }
    float acc = (ax + ay) + (az + aw);

    // softmax over the 16-lane p-group
    float m = acc;
#pragma unroll
    for (int off = 1; off < 16; off <<= 1) m = fmaxf(m, __shfl_xor(m, off));
    float e = __expf((acc - m) * 0.25f);
    float den = e;
#pragma unroll
    for (int off = 1; off < 16; off <<= 1) den += __shfl_xor(den, off);

    prods[(size_t)bs * P + p] = acc;
    wgt  [(size_t)bs * P + p] = e / den;
}

// ---------------------------------------------------------------------------
// Kernel 2: chunk totals T[b,c,p,d] (R4 verbatim). Block = (b,c,half).
// ---------------------------------------------------------------------------
__global__ __launch_bounds__(256) void k_totals(const float* __restrict__ x,
                                                const float* __restrict__ prods,
                                                float* __restrict__ T) {
    int h = blockIdx.x & 1;
    int c = (blockIdx.x >> 1) & (NC - 1);
    int b = blockIdx.x >> 7;
    int d = h * 256 + threadIdx.x;

    float acc[P];
#pragma unroll
    for (int p = 0; p < P; ++p) acc[p] = 0.f;

    int bs0 = b * S + c * CL;
#pragma unroll 4
    for (int i = 0; i < CL; ++i) {
        int bs = bs0 + i;
        float xv = x[(size_t)bs * D + d];
        const float4* pp = (const float4*)(prods + (size_t)bs * P);
        float pr[P];
        ((float4*)pr)[0] = pp[0];
        ((float4*)pr)[1] = pp[1];
        ((float4*)pr)[2] = pp[2];
        ((float4*)pr)[3] = pp[3];
#pragma unroll
        for (int p = 0; p < P; ++p) acc[p] = fmaf(pr[p], xv, acc[p]);
    }
    size_t tb = ((size_t)(b * NC + c)) * (P * D) + d;
#pragma unroll
    for (int p = 0; p < P; ++p) T[tb + p * D] = acc[p];
}

// ---------------------------------------------------------------------------
// Kernel 3: in-place exclusive prefix over chunks (R4 verbatim).
// ---------------------------------------------------------------------------
__global__ __launch_bounds__(256) void k_scan(float* __restrict__ T) {
    int t = blockIdx.x * blockDim.x + threadIdx.x;   // ((b*P+p)*D + d)
    int d = t & (D - 1);
    int p = (t >> 9) & (P - 1);
    int b = t >> 13;
    size_t base = ((size_t)b * NC * P + p) * D + d;
    float run = 0.f;
#pragma unroll 8
    for (int c = 0; c < NC; ++c) {
        size_t idx = base + (size_t)c * (P * D);
        float v = T[idx];
        T[idx] = run;
        run += v;
    }
}

// ---------------------------------------------------------------------------
// Kernel 4: apply (R4 verbatim). Block = (b,c,half), 256 threads.
// ---------------------------------------------------------------------------
__global__ __launch_bounds__(256) void k_apply(const float* __restrict__ x,
                                               const float* __restrict__ prods,
                                               const float* __restrict__ wgt,
                                               const float* __restrict__ T,
                                               float* __restrict__ out) {
    int h = blockIdx.x & 1;
    int c = (blockIdx.x >> 1) & (NC - 1);
    int b = blockIdx.x >> 7;
    int d = h * 256 + threadIdx.x;

    float st[P];
    size_t tb = ((size_t)(b * NC + c)) * (P * D) + d;
#pragma unroll
    for (int p = 0; p < P; ++p) st[p] = T[tb + p * D];

    int bs0 = b * S + c * CL;
#pragma unroll 2
    for (int i = 0; i < CL; ++i) {
        int bs = bs0 + i;
        float xv = x[(size_t)bs * D + d];
        const float4* pp = (const float4*)(prods + (size_t)bs * P);
        const float4* wp = (const float4*)(wgt   + (size_t)bs * P);
        float pr[P], ww[P];
        ((float4*)pr)[0] = pp[0];
        ((float4*)pr)[1] = pp[1];
        ((float4*)pr)[2] = pp[2];
        ((float4*)pr)[3] = pp[3];
        ((float4*)ww)[0] = wp[0];
        ((float4*)ww)[1] = wp[1];
        ((float4*)ww)[2] = wp[2];
        ((float4*)ww)[3] = wp[3];
        float o = 0.f;
#pragma unroll
        for (int p = 0; p < P; ++p) {
            st[p] = fmaf(pr[p], xv, st[p]);
            o = fmaf(ww[p], st[p], o);
        }
        out[(size_t)bs * D + d] = o;
    }
}

extern "C" void kernel_launch(void* const* d_in, const int* in_sizes, int n_in,
                              void* d_out, int out_size, void* d_ws, size_t ws_size,
                              hipStream_t stream) {
    const float* x     = (const float*)d_in[0];
    const float* proxy = (const float*)d_in[1];
    float* out   = (float*)d_out;

    float* prods = (float*)d_ws;                 // B*S*P floats = 512 KiB
    float* wgt   = prods + (size_t)B * S * P;    // 512 KiB
    float* T     = wgt   + (size_t)B * S * P;    // B*NC*P*D floats = 8 MiB

    k_prods <<<(B * S) / 16,      256, 0, stream>>>(x, proxy, prods, wgt);
    k_totals<<<B * NC * 2,        256, 0, stream>>>(x, prods, T);
    k_scan  <<<(B * P * D) / 256, 256, 0, stream>>>(T);
    k_apply <<<B * NC * 2,        256, 0, stream>>>(x, prods, wgt, T, out);
}

// Round 9
// 38.559 us; speedup vs baseline: 1.6887x; 1.6617x over previous
//
#include <hip/hip_runtime.h>
#include <hip/hip_bf16.h>

#define B 4
#define S 2048
#define D 512
#define P 16
#define NC 64   // chunks over sequence
#define CL 32   // chunk length = S/NC

// ---------------------------------------------------------------------------
// Kernel 1: prods[b,s,p] = dot(proxy[p,:], x[b,s,:]); w = softmax_p(prods/4).
// One wave per (b,s) row, R1's fully-coalesced loads (lane owns 8 consecutive
// d). Reduction = R3-verified merge-tree: fold 16 partials into 1 register
// via lane bits 1,2,4,8 (8+4+2+1 shuffles), then 2 shuffles for the 32-lane
// d-slice fold. Lane l ends holding the total for p = l&15.
// ~25 DS ops/row vs ~104 for the R1 butterfly.
// ---------------------------------------------------------------------------
__global__ __launch_bounds__(256) void k_prods(const float* __restrict__ x,
                                               const float* __restrict__ proxy,
                                               float* __restrict__ prods,
                                               float* __restrict__ wgt) {
    int wid  = (blockIdx.x * blockDim.x + threadIdx.x) >> 6;  // bs index
    int lane = threadIdx.x & 63;
    if (wid >= B * S) return;

    const float* xr = x + (size_t)wid * D + lane * 8;
    float4 xa = *(const float4*)xr;
    float4 xb = *(const float4*)(xr + 4);

    float part[P];
#pragma unroll
    for (int p = 0; p < P; ++p) {
        const float* pr = proxy + p * D + lane * 8;
        float4 pa = *(const float4*)pr;
        float4 pb = *(const float4*)(pr + 4);
        part[p] = xa.x*pa.x + xa.y*pa.y + xa.z*pa.z + xa.w*pa.w
                + xb.x*pb.x + xb.y*pb.y + xb.z*pb.z + xb.w*pb.w;
    }

    // merge-tree: fold register count with lane bits 1,2,4,8
    float a8[8];
#pragma unroll
    for (int k = 0; k < 8; ++k) {
        bool hi = lane & 1;
        float mine = hi ? part[2*k+1] : part[2*k];
        float oth  = hi ? part[2*k]   : part[2*k+1];
        a8[k] = mine + __shfl_xor(oth, 1);
    }
    float a4[4];
#pragma unroll
    for (int k = 0; k < 4; ++k) {
        bool hi = lane & 2;
        float mine = hi ? a8[2*k+1] : a8[2*k];
        float oth  = hi ? a8[2*k]   : a8[2*k+1];
        a4[k] = mine + __shfl_xor(oth, 2);
    }
    float a2[2];
#pragma unroll
    for (int k = 0; k < 2; ++k) {
        bool hi = lane & 4;
        float mine = hi ? a4[2*k+1] : a4[2*k];
        float oth  = hi ? a4[2*k]   : a4[2*k+1];
        a2[k] = mine + __shfl_xor(oth, 4);
    }
    float a1;
    {
        bool hi = lane & 8;
        float mine = hi ? a2[1] : a2[0];
        float oth  = hi ? a2[0] : a2[1];
        a1 = mine + __shfl_xor(oth, 8);
    }
    a1 += __shfl_xor(a1, 16);
    a1 += __shfl_xor(a1, 32);
    // lane l holds full dot for p = l & 15

    // softmax over the 16-lane p-group
    float m = a1;
#pragma unroll
    for (int off = 1; off < 16; off <<= 1) m = fmaxf(m, __shfl_xor(m, off));
    float e = __expf((a1 - m) * 0.25f);
    float den = e;
#pragma unroll
    for (int off = 1; off < 16; off <<= 1) den += __shfl_xor(den, off);

    if (lane < P) {
        prods[(size_t)wid * P + lane] = a1;
        wgt  [(size_t)wid * P + lane] = e / den;
    }
}

// ---------------------------------------------------------------------------
// Kernel 2: chunk totals T[b,c,p,d] (R4 verbatim). Block = (b,c,half).
// ---------------------------------------------------------------------------
__global__ __launch_bounds__(256) void k_totals(const float* __restrict__ x,
                                                const float* __restrict__ prods,
                                                float* __restrict__ T) {
    int h = blockIdx.x & 1;
    int c = (blockIdx.x >> 1) & (NC - 1);
    int b = blockIdx.x >> 7;
    int d = h * 256 + threadIdx.x;

    float acc[P];
#pragma unroll
    for (int p = 0; p < P; ++p) acc[p] = 0.f;

    int bs0 = b * S + c * CL;
#pragma unroll 4
    for (int i = 0; i < CL; ++i) {
        int bs = bs0 + i;
        float xv = x[(size_t)bs * D + d];
        const float4* pp = (const float4*)(prods + (size_t)bs * P);
        float pr[P];
        ((float4*)pr)[0] = pp[0];
        ((float4*)pr)[1] = pp[1];
        ((float4*)pr)[2] = pp[2];
        ((float4*)pr)[3] = pp[3];
#pragma unroll
        for (int p = 0; p < P; ++p) acc[p] = fmaf(pr[p], xv, acc[p]);
    }
    size_t tb = ((size_t)(b * NC + c)) * (P * D) + d;
#pragma unroll
    for (int p = 0; p < P; ++p) T[tb + p * D] = acc[p];
}

// ---------------------------------------------------------------------------
// Kernel 3: in-place exclusive prefix over chunks (R4 verbatim).
// ---------------------------------------------------------------------------
__global__ __launch_bounds__(256) void k_scan(float* __restrict__ T) {
    int t = blockIdx.x * blockDim.x + threadIdx.x;   // ((b*P+p)*D + d)
    int d = t & (D - 1);
    int p = (t >> 9) & (P - 1);
    int b = t >> 13;
    size_t base = ((size_t)b * NC * P + p) * D + d;
    float run = 0.f;
#pragma unroll 8
    for (int c = 0; c < NC; ++c) {
        size_t idx = base + (size_t)c * (P * D);
        float v = T[idx];
        T[idx] = run;
        run += v;
    }
}

// ---------------------------------------------------------------------------
// Kernel 4: apply (R4 verbatim). Block = (b,c,half), 256 threads.
// ---------------------------------------------------------------------------
__global__ __launch_bounds__(256) void k_apply(const float* __restrict__ x,
                                               const float* __restrict__ prods,
                                               const float* __restrict__ wgt,
                                               const float* __restrict__ T,
                                               float* __restrict__ out) {
    int h = blockIdx.x & 1;
    int c = (blockIdx.x >> 1) & (NC - 1);
    int b = blockIdx.x >> 7;
    int d = h * 256 + threadIdx.x;

    float st[P];
    size_t tb = ((size_t)(b * NC + c)) * (P * D) + d;
#pragma unroll
    for (int p = 0; p < P; ++p) st[p] = T[tb + p * D];

    int bs0 = b * S + c * CL;
#pragma unroll 2
    for (int i = 0; i < CL; ++i) {
        int bs = bs0 + i;
        float xv = x[(size_t)bs * D + d];
        const float4* pp = (const float4*)(prods + (size_t)bs * P);
        const float4* wp = (const float4*)(wgt   + (size_t)bs * P);
        float pr[P], ww[P];
        ((float4*)pr)[0] = pp[0];
        ((float4*)pr)[1] = pp[1];
        ((float4*)pr)[2] = pp[2];
        ((float4*)pr)[3] = pp[3];
        ((float4*)ww)[0] = wp[0];
        ((float4*)ww)[1] = wp[1];
        ((float4*)ww)[2] = wp[2];
        ((float4*)ww)[3] = wp[3];
        float o = 0.f;
#pragma unroll
        for (int p = 0; p < P; ++p) {
            st[p] = fmaf(pr[p], xv, st[p]);
            o = fmaf(ww[p], st[p], o);
        }
        out[(size_t)bs * D + d] = o;
    }
}

extern "C" void kernel_launch(void* const* d_in, const int* in_sizes, int n_in,
                              void* d_out, int out_size, void* d_ws, size_t ws_size,
                              hipStream_t stream) {
    const float* x     = (const float*)d_in[0];
    const float* proxy = (const float*)d_in[1];
    float* out   = (float*)d_out;

    float* prods = (float*)d_ws;                 // B*S*P floats = 512 KiB
    float* wgt   = prods + (size_t)B * S * P;    // 512 KiB
    float* T     = wgt   + (size_t)B * S * P;    // B*NC*P*D floats = 8 MiB

    k_prods <<<(B * S) / 4,       256, 0, stream>>>(x, proxy, prods, wgt);
    k_totals<<<B * NC * 2,        256, 0, stream>>>(x, prods, T);
    k_scan  <<<(B * P * D) / 256, 256, 0, stream>>>(T);
    k_apply <<<B * NC * 2,        256, 0, stream>>>(x, prods, wgt, T, out);
}

// Round 10
// 36.131 us; speedup vs baseline: 1.8022x; 1.0672x over previous
//
#include <hip/hip_runtime.h>
#include <hip/hip_bf16.h>

#define B 4
#define S 2048
#define D 512
#define P 16
#define NC 64   // chunks over sequence
#define CL 32   // chunk length = S/NC

// ---------------------------------------------------------------------------
// Kernel 1: prods[b,s,p] = dot(proxy[p,:], x[b,s,:]); w = softmax_p(prods/4).
// One wave per 4 consecutive (b,s) rows. Lane owns 8 consecutive d.
// Proxy slices hoisted to VGPRs ONCE per wave (32 float4s) and reused for all
// 4 rows -> proxy L1 traffic drops 256 MB -> 64 MB. Per-row arithmetic is
// R9-verbatim (merge-tree reduction + 16-lane softmax).
// ---------------------------------------------------------------------------
__global__ __launch_bounds__(256) void k_prods(const float* __restrict__ x,
                                               const float* __restrict__ proxy,
                                               float* __restrict__ prods,
                                               float* __restrict__ wgt) {
    const int wave = (blockIdx.x * blockDim.x + threadIdx.x) >> 6;  // 0..2047
    const int lane = threadIdx.x & 63;
    const int bs0  = wave * 4;

    // hoist proxy slices: p-th row, this lane's 8 floats
    float4 pA[P], pB[P];
#pragma unroll
    for (int p = 0; p < P; ++p) {
        const float* pr = proxy + p * D + lane * 8;
        pA[p] = *(const float4*)pr;
        pB[p] = *(const float4*)(pr + 4);
    }

#pragma unroll
    for (int r = 0; r < 4; ++r) {
        const int bs = bs0 + r;
        const float* xr = x + (size_t)bs * D + lane * 8;
        float4 xa = *(const float4*)xr;
        float4 xb = *(const float4*)(xr + 4);

        float part[P];
#pragma unroll
        for (int p = 0; p < P; ++p) {
            part[p] = xa.x*pA[p].x + xa.y*pA[p].y + xa.z*pA[p].z + xa.w*pA[p].w
                    + xb.x*pB[p].x + xb.y*pB[p].y + xb.z*pB[p].z + xb.w*pB[p].w;
        }

        // merge-tree: fold register count with lane bits 1,2,4,8 (R9 verbatim)
        float a8[8];
#pragma unroll
        for (int k = 0; k < 8; ++k) {
            bool hi = lane & 1;
            float mine = hi ? part[2*k+1] : part[2*k];
            float oth  = hi ? part[2*k]   : part[2*k+1];
            a8[k] = mine + __shfl_xor(oth, 1);
        }
        float a4[4];
#pragma unroll
        for (int k = 0; k < 4; ++k) {
            bool hi = lane & 2;
            float mine = hi ? a8[2*k+1] : a8[2*k];
            float oth  = hi ? a8[2*k]   : a8[2*k+1];
            a4[k] = mine + __shfl_xor(oth, 2);
        }
        float a2[2];
#pragma unroll
        for (int k = 0; k < 2; ++k) {
            bool hi = lane & 4;
            float mine = hi ? a4[2*k+1] : a4[2*k];
            float oth  = hi ? a4[2*k]   : a4[2*k+1];
            a2[k] = mine + __shfl_xor(oth, 4);
        }
        float a1;
        {
            bool hi = lane & 8;
            float mine = hi ? a2[1] : a2[0];
            float oth  = hi ? a2[0] : a2[1];
            a1 = mine + __shfl_xor(oth, 8);
        }
        a1 += __shfl_xor(a1, 16);
        a1 += __shfl_xor(a1, 32);
        // lane l holds full dot for p = l & 15

        float m = a1;
#pragma unroll
        for (int off = 1; off < 16; off <<= 1) m = fmaxf(m, __shfl_xor(m, off));
        float e = __expf((a1 - m) * 0.25f);
        float den = e;
#pragma unroll
        for (int off = 1; off < 16; off <<= 1) den += __shfl_xor(den, off);

        if (lane < P) {
            prods[(size_t)bs * P + lane] = a1;
            wgt  [(size_t)bs * P + lane] = e / den;
        }
    }
}

// ---------------------------------------------------------------------------
// Kernel 2: chunk totals T[b,c,p,d] (R4 verbatim). Block = (b,c,half).
// ---------------------------------------------------------------------------
__global__ __launch_bounds__(256) void k_totals(const float* __restrict__ x,
                                                const float* __restrict__ prods,
                                                float* __restrict__ T) {
    int h = blockIdx.x & 1;
    int c = (blockIdx.x >> 1) & (NC - 1);
    int b = blockIdx.x >> 7;
    int d = h * 256 + threadIdx.x;

    float acc[P];
#pragma unroll
    for (int p = 0; p < P; ++p) acc[p] = 0.f;

    int bs0 = b * S + c * CL;
#pragma unroll 4
    for (int i = 0; i < CL; ++i) {
        int bs = bs0 + i;
        float xv = x[(size_t)bs * D + d];
        const float4* pp = (const float4*)(prods + (size_t)bs * P);
        float pr[P];
        ((float4*)pr)[0] = pp[0];
        ((float4*)pr)[1] = pp[1];
        ((float4*)pr)[2] = pp[2];
        ((float4*)pr)[3] = pp[3];
#pragma unroll
        for (int p = 0; p < P; ++p) acc[p] = fmaf(pr[p], xv, acc[p]);
    }
    size_t tb = ((size_t)(b * NC + c)) * (P * D) + d;
#pragma unroll
    for (int p = 0; p < P; ++p) T[tb + p * D] = acc[p];
}

// ---------------------------------------------------------------------------
// Kernel 3: in-place exclusive prefix over chunks (R4 verbatim).
// ---------------------------------------------------------------------------
__global__ __launch_bounds__(256) void k_scan(float* __restrict__ T) {
    int t = blockIdx.x * blockDim.x + threadIdx.x;   // ((b*P+p)*D + d)
    int d = t & (D - 1);
    int p = (t >> 9) & (P - 1);
    int b = t >> 13;
    size_t base = ((size_t)b * NC * P + p) * D + d;
    float run = 0.f;
#pragma unroll 8
    for (int c = 0; c < NC; ++c) {
        size_t idx = base + (size_t)c * (P * D);
        float v = T[idx];
        T[idx] = run;
        run += v;
    }
}

// ---------------------------------------------------------------------------
// Kernel 4: apply (R4 verbatim). Block = (b,c,half), 256 threads.
// ---------------------------------------------------------------------------
__global__ __launch_bounds__(256) void k_apply(const float* __restrict__ x,
                                               const float* __restrict__ prods,
                                               const float* __restrict__ wgt,
                                               const float* __restrict__ T,
                                               float* __restrict__ out) {
    int h = blockIdx.x & 1;
    int c = (blockIdx.x >> 1) & (NC - 1);
    int b = blockIdx.x >> 7;
    int d = h * 256 + threadIdx.x;

    float st[P];
    size_t tb = ((size_t)(b * NC + c)) * (P * D) + d;
#pragma unroll
    for (int p = 0; p < P; ++p) st[p] = T[tb + p * D];

    int bs0 = b * S + c * CL;
#pragma unroll 2
    for (int i = 0; i < CL; ++i) {
        int bs = bs0 + i;
        float xv = x[(size_t)bs * D + d];
        const float4* pp = (const float4*)(prods + (size_t)bs * P);
        const float4* wp = (const float4*)(wgt   + (size_t)bs * P);
        float pr[P], ww[P];
        ((float4*)pr)[0] = pp[0];
        ((float4*)pr)[1] = pp[1];
        ((float4*)pr)[2] = pp[2];
        ((float4*)pr)[3] = pp[3];
        ((float4*)ww)[0] = wp[0];
        ((float4*)ww)[1] = wp[1];
        ((float4*)ww)[2] = wp[2];
        ((float4*)ww)[3] = wp[3];
        float o = 0.f;
#pragma unroll
        for (int p = 0; p < P; ++p) {
            st[p] = fmaf(pr[p], xv, st[p]);
            o = fmaf(ww[p], st[p], o);
        }
        out[(size_t)bs * D + d] = o;
    }
}

extern "C" void kernel_launch(void* const* d_in, const int* in_sizes, int n_in,
                              void* d_out, int out_size, void* d_ws, size_t ws_size,
                              hipStream_t stream) {
    const float* x     = (const float*)d_in[0];
    const float* proxy = (const float*)d_in[1];
    float* out   = (float*)d_out;

    float* prods = (float*)d_ws;                 // B*S*P floats = 512 KiB
    float* wgt   = prods + (size_t)B * S * P;    // 512 KiB
    float* T     = wgt   + (size_t)B * S * P;    // B*NC*P*D floats = 8 MiB

    k_prods <<<(B * S) / 4 / 4,   256, 0, stream>>>(x, proxy, prods, wgt);
    k_totals<<<B * NC * 2,        256, 0, stream>>>(x, prods, T);
    k_scan  <<<(B * P * D) / 256, 256, 0, stream>>>(T);
    k_apply <<<B * NC * 2,        256, 0, stream>>>(x, prods, wgt, T, out);
}